// Round 5
// baseline (372.098 us; speedup 1.0000x reference)
//
#include <hip/hip_runtime.h>
#include <stdint.h>

// Top-k (k=50) temperature sampling, bit-matching
// jax.random.categorical(key(42), topk_mask(logits/T, 50)) with
// jax_threefry_partitionable=True (bit-exact since round 2).
//
// Round-5: split scan (bandwidth) from refine (tiny O(C^2) exact work).
//   init_kernel:  zero per-row candidate counters in d_ws (ws is poisoned).
//   scan_kernel:  2048 blocks x 256 threads, grid-stride over the WHOLE
//                 [256*50257] array as flat float4 (total %4==0, base 16B
//                 aligned -> no prologue). Elements with raw monotone key >=
//                 Flo = key(10.0)-256ulp are pushed (flat idx, val) into a
//                 per-row global buffer; key >= Fhi counted separately.
//                 If cnt_hi >= K the K-th largest raw >= 10.0 and, since
//                 /temp collapses <~1 ulp, every scaled top-k member has raw
//                 key >= Flo => candidate set complete (verified logic, R4).
//   refine_kernel: 256 blocks (one/row): exact IEEE s = l/temp keys, exact
//                 (key,index) rank < K (lax.top_k low-index tie rule),
//                 partitionable-threefry gumbel, argmax with lowest-index
//                 tie-break. Full-row fallback rescan if the filter failed
//                 (never taken for this data; keeps correctness robust).

#define VOCAB 50257
#define BATCH 256
#define TOTAL (BATCH * VOCAB)          // 12,865,792 (divisible by 4)
#define TOTAL4 (TOTAL / 4)             // 3,216,448
#define CAP_ROW 512                    // expected ~312 candidates/row (+11 sigma)
#define FCAP 8192                      // fallback LDS capacity
#define NT_SCAN 256
#define NBLK_SCAN 2048
#define NT_REF 256

__device__ __forceinline__ uint32_t rotl32(uint32_t v, int r) {
  return (v << r) | (v >> (32 - r));
}

// JAX Threefry-2x32-20, key = (0, 42)
__device__ __forceinline__ void threefry2x32_42(uint32_t& x0, uint32_t& x1) {
  const uint32_t ks0 = 0u;
  const uint32_t ks1 = 42u;
  const uint32_t ks2 = ks0 ^ ks1 ^ 0x1BD11BDAu;
  x0 += ks0; x1 += ks1;
#define TF_R(r) { x0 += x1; x1 = rotl32(x1, (r)); x1 ^= x0; }
  TF_R(13) TF_R(15) TF_R(26) TF_R(6)
  x0 += ks1; x1 += ks2 + 1u;
  TF_R(17) TF_R(29) TF_R(16) TF_R(24)
  x0 += ks2; x1 += ks0 + 2u;
  TF_R(13) TF_R(15) TF_R(26) TF_R(6)
  x0 += ks0; x1 += ks1 + 3u;
  TF_R(17) TF_R(29) TF_R(16) TF_R(24)
  x0 += ks1; x1 += ks2 + 4u;
  TF_R(13) TF_R(15) TF_R(26) TF_R(6)
  x0 += ks2; x1 += ks0 + 5u;
#undef TF_R
}

// Gumbel at flat index i (partitionable threefry: counter=u64 i, bits=o0^o1).
__device__ __forceinline__ float gumbel_at(uint32_t flat) {
  uint32_t x0 = 0u, x1 = flat;
  threefry2x32_42(x0, x1);
  uint32_t bits = x0 ^ x1;
  uint32_t fb = (bits >> 9) | 0x3f800000u;
  float f = __uint_as_float(fb) - 1.0f;          // exact
  float u = fmaxf(f, 1.17549435e-38f);
  float t = (float)log((double)u);               // correctly-rounded fp32 path
  float g = (float)(-log((double)(-t)));
  return g;
}

// Monotone float->uint32 key (no NaNs in data).
__device__ __forceinline__ uint32_t fkey(float x) {
  uint32_t u = __float_as_uint(x);
  return (u & 0x80000000u) ? ~u : (u | 0x80000000u);
}

extern "C" __global__ void init_kernel(int* __restrict__ counters) {
  if (threadIdx.x < 2 * BATCH) counters[threadIdx.x] = 0;
}

extern "C" __global__ void __launch_bounds__(NT_SCAN)
scan_kernel(const float* __restrict__ logits,
            int* __restrict__ cnt_lo, int* __restrict__ cnt_hi,
            int* __restrict__ cidx, float* __restrict__ cval) {
  const uint32_t Fhi = 0xC1200000u;            // fkey(10.0f)
  const uint32_t Flo = Fhi - 256u;             // ulp margin for /temp collapse
  const float4* p4 = (const float4*)logits;
  const int stride = NBLK_SCAN * NT_SCAN;
  int v = blockIdx.x * NT_SCAN + threadIdx.x;
  for (; v < TOTAL4; v += stride) {
    float4 x = p4[v];
    uint32_t k0 = fkey(x.x), k1 = fkey(x.y), k2 = fkey(x.z), k3 = fkey(x.w);
#define EMIT(kk, jj, vv)                                                     \
    if (kk >= Flo) {                                                         \
      uint32_t flat = (uint32_t)(4 * v + jj);                                \
      uint32_t row = flat / VOCAB;                                           \
      int p = atomicAdd(&cnt_lo[row], 1);                                    \
      if (p < CAP_ROW) { cidx[row * CAP_ROW + p] = (int)flat;                \
                         cval[row * CAP_ROW + p] = vv; }                     \
      if (kk >= Fhi) atomicAdd(&cnt_hi[row], 1);                             \
    }
    EMIT(k0, 0, x.x) EMIT(k1, 1, x.y) EMIT(k2, 2, x.z) EMIT(k3, 3, x.w)
#undef EMIT
  }
}

extern "C" __global__ void __launch_bounds__(NT_REF)
refine_kernel(const float* __restrict__ logits,
              const float* __restrict__ temp_p,
              const int* __restrict__ topk_p,
              int* __restrict__ out,
              const int* __restrict__ cnt_lo, const int* __restrict__ cnt_hi,
              const int* __restrict__ cidx, const float* __restrict__ cval) {
  const int row = blockIdx.x;
  const int tid = threadIdx.x;
  const float temp = temp_p[0];
  const int K = topk_p[0];
  const float* rowp = logits + (size_t)row * VOCAB;

  __shared__ int s_idx[FCAP];
  __shared__ float s_val[FCAP];
  __shared__ unsigned s_key[FCAP];
  __shared__ int sh_clo, sh_chi;
  __shared__ float red_v[NT_REF];
  __shared__ int red_i[NT_REF];

  int C;
  const int clo = cnt_lo[row];
  const int chi = cnt_hi[row];
  if (chi >= K && clo <= CAP_ROW) {
    // fast path: candidates already collected by scan_kernel
    for (int i = tid; i < clo; i += NT_REF) {
      int flat = cidx[row * CAP_ROW + i];
      s_idx[i] = flat - row * VOCAB;
      s_val[i] = cval[row * CAP_ROW + i];
    }
    C = clo;
  } else {
    // fallback: full-row rescan ladder (unreachable for this input)
    const uint32_t ladder[2] = { 0xC0800000u /*fkey(4.0f)*/, 0u };
    C = 0;
    for (int rung = 0; rung < 2; ++rung) {
      const uint32_t Fh = ladder[rung];
      const uint32_t Fl = (Fh >= 256u) ? (Fh - 256u) : 0u;
      if (tid == 0) { sh_clo = 0; sh_chi = 0; }
      __syncthreads();
      for (int i = tid; i < VOCAB; i += NT_REF) {
        float x = rowp[i];
        uint32_t k = fkey(x);
        if (k >= Fl) {
          int p = atomicAdd(&sh_clo, 1);
          if (p < FCAP) { s_idx[p] = i; s_val[p] = x; }
          if (k >= Fh) atomicAdd(&sh_chi, 1);
        }
      }
      __syncthreads();
      if ((sh_chi >= K && sh_clo <= FCAP) || rung == 1) { C = min(sh_clo, FCAP); break; }
      __syncthreads();
    }
  }
  __syncthreads();

  // exact scaled keys
  for (int i = tid; i < C; i += NT_REF) s_key[i] = fkey(s_val[i] / temp);
  __syncthreads();

  float bestv = -__builtin_huge_valf();
  int besti = 0x7fffffff;
  for (int c = tid; c < C; c += NT_REF) {
    const uint32_t mk = s_key[c];
    const int mi = s_idx[c];
    int rank = 0;
    for (int j = 0; j < C; ++j) {
      uint32_t k = s_key[j];
      rank += (k > mk || (k == mk && s_idx[j] < mi)) ? 1 : 0;
    }
    if (rank < K) {                 // exact lax.top_k membership (low-index ties)
      float s = s_val[c] / temp;
      float v = s + gumbel_at((uint32_t)(row * VOCAB + mi));
      if (v > bestv || (v == bestv && mi < besti)) { bestv = v; besti = mi; }
    }
  }

  red_v[tid] = bestv;
  red_i[tid] = besti;
  __syncthreads();
  for (int off = NT_REF / 2; off > 0; off >>= 1) {
    if (tid < off) {
      float v2 = red_v[tid + off];
      int i2 = red_i[tid + off];
      if (v2 > red_v[tid] || (v2 == red_v[tid] && i2 < red_i[tid])) {
        red_v[tid] = v2;
        red_i[tid] = i2;
      }
    }
    __syncthreads();
  }
  if (tid == 0) out[row] = red_i[0];
}

extern "C" void kernel_launch(void* const* d_in, const int* in_sizes, int n_in,
                              void* d_out, int out_size, void* d_ws, size_t ws_size,
                              hipStream_t stream) {
  const float* logits = (const float*)d_in[0];
  const float* temp_p = (const float*)d_in[1];
  const int* topk_p = (const int*)d_in[2];
  int* out = (int*)d_out;

  // ws layout: cnt_lo[256] | cnt_hi[256] | cidx[256*CAP_ROW] | cval[256*CAP_ROW]
  char* ws = (char*)d_ws;
  int* cnt_lo = (int*)ws;
  int* cnt_hi = cnt_lo + BATCH;
  int* cidx = cnt_hi + BATCH;
  float* cval = (float*)(cidx + BATCH * CAP_ROW);

  hipLaunchKernelGGL(init_kernel, dim3(1), dim3(512), 0, stream, cnt_lo);
  hipLaunchKernelGGL(scan_kernel, dim3(NBLK_SCAN), dim3(NT_SCAN), 0, stream,
                     logits, cnt_lo, cnt_hi, cidx, cval);
  hipLaunchKernelGGL(refine_kernel, dim3(BATCH), dim3(NT_REF), 0, stream,
                     logits, temp_p, topk_p, out, cnt_lo, cnt_hi, cidx, cval);
}

// Round 6
// 145.559 us; speedup vs baseline: 2.5563x; 2.5563x over previous
//
#include <hip/hip_runtime.h>
#include <stdint.h>

// Top-k (k=50) temperature sampling, bit-matching
// jax.random.categorical(key(42), topk_mask(logits/T, 50)) with
// jax_threefry_partitionable=True (bit-exact since round 2).
//
// Round-6: R5's split structure, but WITHOUT per-element global atomics
// (R5 post-mortem: 160K contended device-scope atomics onto ~32 cache lines
// serialized at ~100ns/op at the coherence point = the entire 248us).
//   scan_kernel: 2048 blocks x 256 threads; block b owns a contiguous chunk
//     of float4s (spans <= 2 rows). Candidates (raw key >= Flo) are pushed to
//     an LDS buffer with LDS atomics; per-row lo/hi counts kept in LDS.
//     At block end: ONE global atomicAdd per (block,row) reserves a slot
//     range in the per-row candidate array (counters padded to 128B), then a
//     bulk copy-out. <= 4 global atomics per block (~8K total, uncontended).
//   refine_kernel (verified logic, unchanged): exact IEEE s=l/temp keys,
//     exact (key,index) rank < K (lax.top_k low-index tie rule),
//     partitionable-threefry gumbel, argmax with lowest-index tie-break.
//     Any cap overflow or filter failure -> full-row fallback rescan.

#define VOCAB 50257
#define BATCH 256
#define TOTAL (BATCH * VOCAB)          // 12,865,792 (divisible by 4)
#define TOTAL4 (TOTAL / 4)             // 3,216,448
#define NBLK_SCAN 2048
#define NT_SCAN 256
#define CHUNK4 ((TOTAL4 + NBLK_SCAN - 1) / NBLK_SCAN)   // 1571 float4s
#define CAP_ROW 512                    // expected ~312 candidates/row
#define LCAP 1024                      // per-block LDS candidate cap (~39 expected)
#define FCAP 8192                      // fallback LDS capacity
#define NT_REF 256
#define CSTRIDE 32                     // counter padding: 32 ints = 128 B/row

__device__ __forceinline__ uint32_t rotl32(uint32_t v, int r) {
  return (v << r) | (v >> (32 - r));
}

// JAX Threefry-2x32-20, key = (0, 42)
__device__ __forceinline__ void threefry2x32_42(uint32_t& x0, uint32_t& x1) {
  const uint32_t ks0 = 0u;
  const uint32_t ks1 = 42u;
  const uint32_t ks2 = ks0 ^ ks1 ^ 0x1BD11BDAu;
  x0 += ks0; x1 += ks1;
#define TF_R(r) { x0 += x1; x1 = rotl32(x1, (r)); x1 ^= x0; }
  TF_R(13) TF_R(15) TF_R(26) TF_R(6)
  x0 += ks1; x1 += ks2 + 1u;
  TF_R(17) TF_R(29) TF_R(16) TF_R(24)
  x0 += ks2; x1 += ks0 + 2u;
  TF_R(13) TF_R(15) TF_R(26) TF_R(6)
  x0 += ks0; x1 += ks1 + 3u;
  TF_R(17) TF_R(29) TF_R(16) TF_R(24)
  x0 += ks1; x1 += ks2 + 4u;
  TF_R(13) TF_R(15) TF_R(26) TF_R(6)
  x0 += ks2; x1 += ks0 + 5u;
#undef TF_R
}

// Gumbel at flat index i (partitionable threefry: counter=u64 i, bits=o0^o1).
__device__ __forceinline__ float gumbel_at(uint32_t flat) {
  uint32_t x0 = 0u, x1 = flat;
  threefry2x32_42(x0, x1);
  uint32_t bits = x0 ^ x1;
  uint32_t fb = (bits >> 9) | 0x3f800000u;
  float f = __uint_as_float(fb) - 1.0f;          // exact
  float u = fmaxf(f, 1.17549435e-38f);
  float t = (float)log((double)u);               // correctly-rounded fp32 path
  float g = (float)(-log((double)(-t)));
  return g;
}

// Monotone float->uint32 key (no NaNs in data).
__device__ __forceinline__ uint32_t fkey(float x) {
  uint32_t u = __float_as_uint(x);
  return (u & 0x80000000u) ? ~u : (u | 0x80000000u);
}

extern "C" __global__ void init_kernel(int* __restrict__ counters) {
  int i = blockIdx.x * 256 + threadIdx.x;
  if (i < 2 * BATCH * CSTRIDE) counters[i] = 0;
}

extern "C" __global__ void __launch_bounds__(NT_SCAN)
scan_kernel(const float* __restrict__ logits,
            int* __restrict__ cnt_lo, int* __restrict__ cnt_hi,
            int* __restrict__ cidx, float* __restrict__ cval) {
  const uint32_t Fhi = 0xC1200000u;            // fkey(10.0f)
  const uint32_t Flo = Fhi - 256u;             // ulp margin for /temp collapse
  const float4* p4 = (const float4*)logits;
  const int tid = threadIdx.x;

  const int start = blockIdx.x * CHUNK4;
  const int end = min(start + CHUNK4, TOTAL4);
  const int rowA = (4 * start) / VOCAB;        // chunk spans <= 2 rows
  const int rowB = (4 * end - 1) / VOCAB;

  __shared__ int buf_flat[LCAP];
  __shared__ float buf_val[LCAP];
  __shared__ int nbuf, nloA, nloB, nhiA, nhiB;
  __shared__ int baseA, baseB, wA, wB;

  if (tid == 0) { nbuf = 0; nloA = 0; nloB = 0; nhiA = 0; nhiB = 0; wA = 0; wB = 0; }
  __syncthreads();

  // ---- pure-stream scan; rare LDS pushes only ----
  for (int v = start + tid; v < end; v += NT_SCAN) {
    float4 x = p4[v];
    uint32_t k0 = fkey(x.x), k1 = fkey(x.y), k2 = fkey(x.z), k3 = fkey(x.w);
#define EMIT(kk, jj, vv)                                                     \
    if (kk >= Flo) {                                                         \
      int flat = 4 * v + jj;                                                 \
      bool isA = (flat / VOCAB) == rowA;                                     \
      atomicAdd(isA ? &nloA : &nloB, 1);                                     \
      if (kk >= Fhi) atomicAdd(isA ? &nhiA : &nhiB, 1);                      \
      int p = atomicAdd(&nbuf, 1);                                           \
      if (p < LCAP) { buf_flat[p] = flat; buf_val[p] = vv; }                 \
    }
    EMIT(k0, 0, x.x) EMIT(k1, 1, x.y) EMIT(k2, 2, x.z) EMIT(k3, 3, x.w)
#undef EMIT
  }
  __syncthreads();

  const bool ovf = nbuf > LCAP;
  // ---- reserve global slot ranges: <= 4 global atomics per block ----
  if (tid == 0) {
    int addA = ovf ? (CAP_ROW + 1) : nloA;     // overflow forces refine fallback
    baseA = (nloA > 0 || ovf) ? atomicAdd(&cnt_lo[rowA * CSTRIDE], addA) : 0;
    if (nhiA > 0) atomicAdd(&cnt_hi[rowA * CSTRIDE], nhiA);
    if (rowB != rowA) {
      int addB = ovf ? (CAP_ROW + 1) : nloB;
      baseB = (nloB > 0 || ovf) ? atomicAdd(&cnt_lo[rowB * CSTRIDE], addB) : 0;
      if (nhiB > 0) atomicAdd(&cnt_hi[rowB * CSTRIDE], nhiB);
    }
  }
  __syncthreads();

  // ---- bulk copy-out ----
  const int stored = min(nbuf, LCAP);
  for (int i = tid; i < stored; i += NT_SCAN) {
    int flat = buf_flat[i];
    bool isA = (flat / VOCAB) == rowA;
    int p = atomicAdd(isA ? &wA : &wB, 1);     // LDS rank (order irrelevant)
    int slot = (isA ? baseA : baseB) + p;
    int r = isA ? rowA : rowB;
    if (slot < CAP_ROW) {
      cidx[r * CAP_ROW + slot] = flat;
      cval[r * CAP_ROW + slot] = buf_val[i];
    }
  }
}

extern "C" __global__ void __launch_bounds__(NT_REF)
refine_kernel(const float* __restrict__ logits,
              const float* __restrict__ temp_p,
              const int* __restrict__ topk_p,
              int* __restrict__ out,
              const int* __restrict__ cnt_lo, const int* __restrict__ cnt_hi,
              const int* __restrict__ cidx, const float* __restrict__ cval) {
  const int row = blockIdx.x;
  const int tid = threadIdx.x;
  const float temp = temp_p[0];
  const int K = topk_p[0];
  const float* rowp = logits + (size_t)row * VOCAB;

  __shared__ int s_idx[FCAP];
  __shared__ float s_val[FCAP];
  __shared__ unsigned s_key[FCAP];
  __shared__ int sh_clo, sh_chi;
  __shared__ float red_v[NT_REF];
  __shared__ int red_i[NT_REF];

  int C;
  const int clo = cnt_lo[row * CSTRIDE];
  const int chi = cnt_hi[row * CSTRIDE];
  if (chi >= K && clo <= CAP_ROW) {
    // fast path: candidates collected by scan_kernel
    for (int i = tid; i < clo; i += NT_REF) {
      s_idx[i] = cidx[row * CAP_ROW + i] - row * VOCAB;
      s_val[i] = cval[row * CAP_ROW + i];
    }
    C = clo;
  } else {
    // fallback: full-row rescan ladder (unreachable for this input)
    const uint32_t ladder[2] = { 0xC0800000u /*fkey(4.0f)*/, 0u };
    C = 0;
    for (int rung = 0; rung < 2; ++rung) {
      const uint32_t Fh = ladder[rung];
      const uint32_t Fl = (Fh >= 256u) ? (Fh - 256u) : 0u;
      if (tid == 0) { sh_clo = 0; sh_chi = 0; }
      __syncthreads();
      for (int i = tid; i < VOCAB; i += NT_REF) {
        float x = rowp[i];
        uint32_t k = fkey(x);
        if (k >= Fl) {
          int p = atomicAdd(&sh_clo, 1);
          if (p < FCAP) { s_idx[p] = i; s_val[p] = x; }
          if (k >= Fh) atomicAdd(&sh_chi, 1);
        }
      }
      __syncthreads();
      if ((sh_chi >= K && sh_clo <= FCAP) || rung == 1) { C = min(sh_clo, FCAP); break; }
      __syncthreads();
    }
  }
  __syncthreads();

  // exact scaled keys
  for (int i = tid; i < C; i += NT_REF) s_key[i] = fkey(s_val[i] / temp);
  __syncthreads();

  float bestv = -__builtin_huge_valf();
  int besti = 0x7fffffff;
  for (int c = tid; c < C; c += NT_REF) {
    const uint32_t mk = s_key[c];
    const int mi = s_idx[c];
    int rank = 0;
    for (int j = 0; j < C; ++j) {
      uint32_t k = s_key[j];
      rank += (k > mk || (k == mk && s_idx[j] < mi)) ? 1 : 0;
    }
    if (rank < K) {                 // exact lax.top_k membership (low-index ties)
      float s = s_val[c] / temp;
      float v = s + gumbel_at((uint32_t)(row * VOCAB + mi));
      if (v > bestv || (v == bestv && mi < besti)) { bestv = v; besti = mi; }
    }
  }

  red_v[tid] = bestv;
  red_i[tid] = besti;
  __syncthreads();
  for (int off = NT_REF / 2; off > 0; off >>= 1) {
    if (tid < off) {
      float v2 = red_v[tid + off];
      int i2 = red_i[tid + off];
      if (v2 > red_v[tid] || (v2 == red_v[tid] && i2 < red_i[tid])) {
        red_v[tid] = v2;
        red_i[tid] = i2;
      }
    }
    __syncthreads();
  }
  if (tid == 0) out[row] = red_i[0];
}

extern "C" void kernel_launch(void* const* d_in, const int* in_sizes, int n_in,
                              void* d_out, int out_size, void* d_ws, size_t ws_size,
                              hipStream_t stream) {
  const float* logits = (const float*)d_in[0];
  const float* temp_p = (const float*)d_in[1];
  const int* topk_p = (const int*)d_in[2];
  int* out = (int*)d_out;

  // ws: cnt_lo[256*32] | cnt_hi[256*32] | cidx[256*512] | cval[256*512]
  int* cnt_lo = (int*)d_ws;
  int* cnt_hi = cnt_lo + BATCH * CSTRIDE;
  int* cidx = cnt_hi + BATCH * CSTRIDE;
  float* cval = (float*)(cidx + BATCH * CAP_ROW);

  hipLaunchKernelGGL(init_kernel, dim3((2 * BATCH * CSTRIDE + 255) / 256),
                     dim3(256), 0, stream, cnt_lo);
  hipLaunchKernelGGL(scan_kernel, dim3(NBLK_SCAN), dim3(NT_SCAN), 0, stream,
                     logits, cnt_lo, cnt_hi, cidx, cval);
  hipLaunchKernelGGL(refine_kernel, dim3(BATCH), dim3(NT_REF), 0, stream,
                     logits, temp_p, topk_p, out, cnt_lo, cnt_hi, cidx, cval);
}

// Round 8
// 115.305 us; speedup vs baseline: 3.2271x; 1.2624x over previous
//
#include <hip/hip_runtime.h>
#include <stdint.h>

// Top-k (k=50) temperature sampling, bit-matching
// jax.random.categorical(key(42), topk_mask(logits/T, 50)) with
// jax_threefry_partitionable=True (bit-exact since round 2).
//
// Round-8 = round-7 intent with the macro hygiene bug fixed ((x).x expanded
// to (a).a — field accessor token collided with macro param). Helpers are
// now real inline functions.
//
// One fused dispatch, one 1024-thread block per row:
//   Scan: x4-unrolled float4 loads hoisted before any filtering (4 loads in
//         flight/wave for MLP); candidates with raw monotone key >=
//         Flo = key(10.0)-256ulp pushed to LDS; count >= Fhi separately.
//         cnt_hi >= K proves the candidate set contains every scaled top-k
//         member (division collapses <~1 ulp; 256-ulp raw margin).
//   Fallback (unreachable here): R3-verified 4096-bin histogram radix select.
//   Refine (verified): exact IEEE s = l/temp keys, exact (key,index) rank< K
//         (lax.top_k low-index tie rule), partitionable-threefry gumbel,
//         argmax with lowest-index tie-break (jnp.argmax rule).

#define VOCAB 50257
#define BATCH 256
#define NT 1024
#define CAP 2048          // candidate cap (expected ~312/row)
#define NBINS 4096

__device__ __forceinline__ uint32_t rotl32(uint32_t v, int r) {
  return (v << r) | (v >> (32 - r));
}

// JAX Threefry-2x32-20, key = (0, 42)
__device__ __forceinline__ void threefry2x32_42(uint32_t& x0, uint32_t& x1) {
  const uint32_t ks0 = 0u;
  const uint32_t ks1 = 42u;
  const uint32_t ks2 = ks0 ^ ks1 ^ 0x1BD11BDAu;
  x0 += ks0; x1 += ks1;
#define TF_R(r) { x0 += x1; x1 = rotl32(x1, (r)); x1 ^= x0; }
  TF_R(13) TF_R(15) TF_R(26) TF_R(6)
  x0 += ks1; x1 += ks2 + 1u;
  TF_R(17) TF_R(29) TF_R(16) TF_R(24)
  x0 += ks2; x1 += ks0 + 2u;
  TF_R(13) TF_R(15) TF_R(26) TF_R(6)
  x0 += ks0; x1 += ks1 + 3u;
  TF_R(17) TF_R(29) TF_R(16) TF_R(24)
  x0 += ks1; x1 += ks2 + 4u;
  TF_R(13) TF_R(15) TF_R(26) TF_R(6)
  x0 += ks2; x1 += ks0 + 5u;
#undef TF_R
}

// Gumbel at flat index i (partitionable threefry: counter=u64 i, bits=o0^o1).
__device__ __forceinline__ float gumbel_at(uint32_t flat) {
  uint32_t x0 = 0u, x1 = flat;
  threefry2x32_42(x0, x1);
  uint32_t bits = x0 ^ x1;
  uint32_t fb = (bits >> 9) | 0x3f800000u;
  float f = __uint_as_float(fb) - 1.0f;          // exact
  float u = fmaxf(f, 1.17549435e-38f);
  float t = (float)log((double)u);               // correctly-rounded fp32 path
  float g = (float)(-log((double)(-t)));
  return g;
}

// Monotone float->uint32 key (no NaNs in data).
__device__ __forceinline__ uint32_t fkey(float x) {
  uint32_t u = __float_as_uint(x);
  return (u & 0x80000000u) ? ~u : (u | 0x80000000u);
}

#define FHI 0xC1200000u                          // fkey(10.0f)
#define FLO (FHI - 256u)                         // ulp margin for /temp collapse

__device__ __forceinline__ void emit1(uint32_t kk, int ii, float vv,
                                      int* s_idx, float* s_val,
                                      int* sh_cnt, int* sh_hi) {
  if (kk >= FLO) {
    int p = atomicAdd(sh_cnt, 1);
    if (p < CAP) { s_idx[p] = ii; s_val[p] = vv; }
    if (kk >= FHI) atomicAdd(sh_hi, 1);
  }
}

__device__ __forceinline__ void proc4(float4 q, int base,
                                      int* s_idx, float* s_val,
                                      int* sh_cnt, int* sh_hi) {
  uint32_t k0 = fkey(q.x), k1 = fkey(q.y), k2 = fkey(q.z), k3 = fkey(q.w);
  emit1(k0, base + 0, q.x, s_idx, s_val, sh_cnt, sh_hi);
  emit1(k1, base + 1, q.y, s_idx, s_val, sh_cnt, sh_hi);
  emit1(k2, base + 2, q.z, s_idx, s_val, sh_cnt, sh_hi);
  emit1(k3, base + 3, q.w, s_idx, s_val, sh_cnt, sh_hi);
}

extern "C" __global__ void __launch_bounds__(NT)
topk_sample_kernel(const float* __restrict__ logits,
                   const float* __restrict__ temp_p,
                   const int* __restrict__ topk_p,
                   int* __restrict__ out) {
  const int row = blockIdx.x;
  const int tid = threadIdx.x;
  const float temp = temp_p[0];
  const int K = topk_p[0];
  const float* rowp = logits + (size_t)row * VOCAB;

  // rows are only 4B-aligned (VOCAB%4==1): scalar prologue to 16B.
  const int pc = (4 - (row & 3)) & 3;
  const int nv4 = (VOCAB - pc) >> 2;
  const int tailbase = pc + (nv4 << 2);
  const int tailc = VOCAB - tailbase;            // 0..3
  const float4* body = (const float4*)(rowp + pc);

  __shared__ int s_idx[CAP];
  __shared__ float s_val[CAP];
  __shared__ unsigned s_key[CAP];
  __shared__ unsigned scratch[NBINS];            // hist (fallback) / reduction
  __shared__ unsigned wtot[16], aboveWave[16];
  __shared__ int sh_cnt, sh_hi, sh_tb, sh_total;
  float* red_v = (float*)scratch;                // aliased: used after hist
  int* red_i = (int*)(scratch + NT);

  if (tid == 0) { sh_cnt = 0; sh_hi = 0; }
  __syncthreads();

  // ---- Phase 1: filtered scan, loads hoisted for MLP ----
  if (tid < pc) {
    float x = rowp[tid];
    emit1(fkey(x), tid, x, s_idx, s_val, &sh_cnt, &sh_hi);
  }
  int v = tid;
  for (; v + 3 * NT < nv4; v += 4 * NT) {
    float4 a = body[v];
    float4 b = body[v + NT];
    float4 c = body[v + 2 * NT];
    float4 d = body[v + 3 * NT];
    proc4(a, pc + 4 * v, s_idx, s_val, &sh_cnt, &sh_hi);
    proc4(b, pc + 4 * (v + NT), s_idx, s_val, &sh_cnt, &sh_hi);
    proc4(c, pc + 4 * (v + 2 * NT), s_idx, s_val, &sh_cnt, &sh_hi);
    proc4(d, pc + 4 * (v + 3 * NT), s_idx, s_val, &sh_cnt, &sh_hi);
  }
  for (; v < nv4; v += NT) {
    float4 a = body[v];
    proc4(a, pc + 4 * v, s_idx, s_val, &sh_cnt, &sh_hi);
  }
  if (tid < tailc) {
    float x = rowp[tailbase + tid];
    emit1(fkey(x), tailbase + tid, x, s_idx, s_val, &sh_cnt, &sh_hi);
  }
  __syncthreads();

  int C;
  if (sh_hi >= K && sh_cnt <= CAP) {
    C = sh_cnt;                                  // fast path (always, this data)
  } else {
    // ---- Fallback: R3-verified 4096-bin histogram radix select ----
    const int lane = tid & 63;
    const int wave = tid >> 6;
    for (int b = tid; b < NBINS; b += NT) scratch[b] = 0u;
    __syncthreads();
    for (int i = tid; i < VOCAB; i += NT) {
      uint32_t k = fkey(rowp[i]);
      atomicAdd(&scratch[k >> 20], 1u);
    }
    __syncthreads();
    unsigned p = scratch[4 * tid] + scratch[4 * tid + 1] +
                 scratch[4 * tid + 2] + scratch[4 * tid + 3];
    unsigned sv = p;
    for (int off = 1; off < 64; off <<= 1) {
      unsigned o = (unsigned)__shfl_down((int)sv, off);
      if (lane + off < 64) sv += o;              // wave inclusive suffix sum
    }
    if (lane == 0) wtot[wave] = sv;
    __syncthreads();
    if (tid == 0) {
      unsigned acc = 0;
      for (int w = 15; w >= 0; --w) { aboveWave[w] = acc; acc += wtot[w]; }
      sh_total = (int)acc;
    }
    __syncthreads();
    unsigned above = aboveWave[wave] + (sv - p);
    if (above < (unsigned)K && above + p >= (unsigned)K) {
      int need = K - (int)above;
      for (int b = 3; b >= 0; --b) {
        unsigned c = scratch[4 * tid + b];
        if (c >= (unsigned)need) { sh_tb = 4 * tid + b; break; }
        need -= (int)c;
      }
    }
    __syncthreads();
    const uint32_t cutk = (uint32_t)max(sh_tb - 1, 0) << 20;
    if (tid == 0) sh_cnt = 0;
    __syncthreads();
    for (int i = tid; i < VOCAB; i += NT) {
      float x = rowp[i];
      if (fkey(x) >= cutk) {
        int q = atomicAdd(&sh_cnt, 1);
        if (q < CAP) { s_idx[q] = i; s_val[q] = x; }
      }
    }
    __syncthreads();
    C = min(sh_cnt, CAP);
  }

  // ---- Phase 2: refine (exact keys, exact rank, gumbel, argmax) ----
  for (int i = tid; i < C; i += NT) s_key[i] = fkey(s_val[i] / temp);
  __syncthreads();

  float bestv = -__builtin_huge_valf();
  int besti = 0x7fffffff;
  for (int c = tid; c < C; c += NT) {
    const uint32_t mk = s_key[c];
    const int mi = s_idx[c];
    int rank = 0;
    for (int j = 0; j < C; ++j) {
      uint32_t k = s_key[j];
      rank += (k > mk || (k == mk && s_idx[j] < mi)) ? 1 : 0;
    }
    if (rank < K) {                              // exact lax.top_k membership
      float s = s_val[c] / temp;
      float g = s + gumbel_at((uint32_t)(row * VOCAB + mi));
      if (g > bestv || (g == bestv && mi < besti)) { bestv = g; besti = mi; }
    }
  }

  red_v[tid] = bestv;
  red_i[tid] = besti;
  __syncthreads();
  for (int off = NT / 2; off > 0; off >>= 1) {
    if (tid < off) {
      float v2 = red_v[tid + off];
      int i2 = red_i[tid + off];
      if (v2 > red_v[tid] || (v2 == red_v[tid] && i2 < red_i[tid])) {
        red_v[tid] = v2;
        red_i[tid] = i2;
      }
    }
    __syncthreads();
  }
  if (tid == 0) out[row] = red_i[0];
}

extern "C" void kernel_launch(void* const* d_in, const int* in_sizes, int n_in,
                              void* d_out, int out_size, void* d_ws, size_t ws_size,
                              hipStream_t stream) {
  const float* logits = (const float*)d_in[0];
  const float* temp_p = (const float*)d_in[1];
  const int* topk_p = (const int*)d_in[2];
  int* out = (int*)d_out;
  hipLaunchKernelGGL(topk_sample_kernel, dim3(BATCH), dim3(NT), 0, stream,
                     logits, temp_p, topk_p, out);
}